// Round 18
// baseline (424.836 us; speedup 1.0000x reference)
//
#include <hip/hip_runtime.h>

#define BATCH 8
#define NPTS 4096
#define DIM 64
#define KNN 20
#define BI 64                // i-rows per block (2 tiles x 32)
#define CJ 128               // j-chunk
#define MCT 28               // per-lane sorted list (per i, jh, hf quarter)
#define MROW 32              // row candidates after 4-way merge
#define NTH 256
#define NCHUNK (NPTS / CJ)   // 32
#define PIT 42               // LDS row pitch in u32 words (2-way-free banks)
#define RESC 8               // rescore candidates per thread

typedef unsigned long long ull;
typedef unsigned int u32;
typedef __attribute__((ext_vector_type(8))) __bf16 bf16x8;
typedef __attribute__((ext_vector_type(16))) float f32x16;

union FragU { bf16x8 v; uint2 u2[2]; };

// ===== VALIDATED R11 recipes (bit-exact vs checker) — do not touch =====
__device__ __forceinline__ float np_sumsq64(const float* __restrict__ xv) {
#pragma clang fp contract(off)
    float r[8];
#pragma unroll
    for (int l = 0; l < 8; ++l) { float v = xv[1 + l]; r[l] = v * v; }
#pragma unroll
    for (int t = 1; t < 7; ++t)
#pragma unroll
        for (int l = 0; l < 8; ++l) {
            float v = xv[1 + 8 * t + l];
            float p = v * v;
            r[l] = r[l] + p;
        }
    float res = ((r[0] + r[1]) + (r[2] + r[3])) + ((r[4] + r[5]) + (r[6] + r[7]));
#pragma unroll
    for (int d = 57; d < 64; ++d) { float v = xv[d]; float p = v * v; res = res + p; }
    float a0 = xv[0] * xv[0];
    return a0 + res;
}

__device__ __forceinline__ float np_blas_dot64(const float* __restrict__ xi_,
                                               const float* __restrict__ xj_) {
    float acc = 0.f;
#pragma unroll
    for (int d = 0; d < DIM; ++d) acc = fmaf(xi_[d], xj_[d], acc);
    return acc;
}
// =======================================================================

__device__ __forceinline__ u32 packw(float a, float b) {
    return (__float_as_uint(b) & 0xFFFF0000u) | (__float_as_uint(a) >> 16);
}

__global__ __launch_bounds__(NTH, 2) void edge_knn_kernel(const float* __restrict__ x,
                                                          float* __restrict__ out) {
    // LDS: (64 + 2*128) * 42 words = 13440 w = 53760 B -> 2 blocks/CU
    __shared__ __align__(16) u32 sPool[(BI + 2 * CJ) * PIT];
    u32* sXi = sPool;                       // [64][42]
    u32* sXj = sPool + BI * PIT;            // [2][128][42]
    u32* mbk = sPool + BI * PIT;            // overlay after loop: 64*4*28 = 7168 w
    int* sFin = (int*)(sPool + BI * PIT + BI * 4 * MCT);  // 64*32 = 2048 w

    const int tid = threadIdx.x;
    const int blk = blockIdx.x;
    const int b   = blk >> 6;               // / (4096/64)
    const int i0  = (blk & 63) * BI;
    const float* xb = x + (size_t)b * NPTS * DIM;

    const int r2 = tid >> 1, h2 = tid & 1;

    // write one staged half-row (32 f32 in sv[8]) as bf16 + aug into buf
    auto stage_write = [&](int buf, const float4* sv) {
        u32* dst = sXj + (size_t)buf * CJ * PIT + r2 * PIT + h2 * 16;
        float ps = 0.f;
#pragma unroll
        for (int q = 0; q < 8; ++q) {
            ps = fmaf(sv[q].x, sv[q].x, ps); ps = fmaf(sv[q].y, sv[q].y, ps);
            ps = fmaf(sv[q].z, sv[q].z, ps); ps = fmaf(sv[q].w, sv[q].w, ps);
        }
#pragma unroll
        for (int q = 0; q < 4; ++q) {
            uint2 p0, p1;
            p0.x = packw(sv[2 * q].x, sv[2 * q].y);
            p0.y = packw(sv[2 * q].z, sv[2 * q].w);
            p1.x = packw(sv[2 * q + 1].x, sv[2 * q + 1].y);
            p1.y = packw(sv[2 * q + 1].z, sv[2 * q + 1].w);
            *(uint2*)&dst[q * 4]     = p0;
            *(uint2*)&dst[q * 4 + 2] = p1;
        }
        ps += __shfl_xor(ps, 1, 2);
        if (h2 == 0) {  // aug: word32 = (sqj_hi, sqj_lo), word33 = (1,1)
            u32 hib = __float_as_uint(ps) & 0xFFFF0000u;
            float lo = ps - __uint_as_float(hib);
            uint2 aug;
            aug.x = (__float_as_uint(lo) & 0xFFFF0000u) | (hib >> 16);
            aug.y = 0x3F803F80u;
            *(uint2*)&sXj[(size_t)buf * CJ * PIT + r2 * PIT + 32] = aug;
        }
    };

    // ---- prologue: Xi tile (-2*xi bf16 + aug), zero-fill, chunk-0 staging ----
    if (tid < 2 * BI) {
        const float* src = xb + (size_t)(i0 + r2) * DIM + h2 * 32;
        u32* dst = sXi + r2 * PIT + h2 * 16;
        float ps = 0.f;
#pragma unroll
        for (int q = 0; q < 4; ++q) {
            float4 va = *(const float4*)(src + q * 8);
            float4 vb = *(const float4*)(src + q * 8 + 4);
            ps = fmaf(va.x, va.x, ps); ps = fmaf(va.y, va.y, ps);
            ps = fmaf(va.z, va.z, ps); ps = fmaf(va.w, va.w, ps);
            ps = fmaf(vb.x, vb.x, ps); ps = fmaf(vb.y, vb.y, ps);
            ps = fmaf(vb.z, vb.z, ps); ps = fmaf(vb.w, vb.w, ps);
            uint2 p0, p1;
            p0.x = packw(-2.f * va.x, -2.f * va.y);
            p0.y = packw(-2.f * va.z, -2.f * va.w);
            p1.x = packw(-2.f * vb.x, -2.f * vb.y);
            p1.y = packw(-2.f * vb.z, -2.f * vb.w);
            *(uint2*)&dst[q * 4]     = p0;
            *(uint2*)&dst[q * 4 + 2] = p1;
        }
        ps += __shfl_xor(ps, 1, 2);
        if (h2 == 0) {  // aug: word32 = (1,1), word33 = (sqi1_hi, sqi1_lo)
            float sq1 = ps + 1.0f;
            u32 hib = __float_as_uint(sq1) & 0xFFFF0000u;
            float lo = sq1 - __uint_as_float(hib);
            uint2 aug;
            aug.x = 0x3F803F80u;
            aug.y = (__float_as_uint(lo) & 0xFFFF0000u) | (hib >> 16);
            *(uint2*)&sXi[r2 * PIT + 32] = aug;
        }
    }
    // zero words 34..39 of every row (Xi + both Xj buffers)
    for (int idx = tid; idx < (BI + 2 * CJ) * 3; idx += NTH) {
        int row = idx / 3, part = idx % 3;
        *(uint2*)&sPool[row * PIT + 34 + part * 2] = make_uint2(0u, 0u);
    }
    {   // stage chunk 0 into buf 0
        const float* src = xb + (size_t)r2 * DIM + h2 * 32;
        float4 sv[8];
#pragma unroll
        for (int q = 0; q < 8; ++q) sv[q] = *(const float4*)(src + q * 4);
        stage_write(0, sv);
    }
    __syncthreads();

    const int lane = tid & 63, wv = tid >> 6;
    const int it = wv >> 1, jh = wv & 1;     // i-tile, j-half
    const int nrow = lane & 31, hf = lane >> 5;

    // hoist Xi (B-operand) fragments into registers for the whole kernel
    uint2 bf[5][2];
    {
        const u32* irow = sXi + (it * 32 + nrow) * PIT;
#pragma unroll
        for (int ks = 0; ks < 5; ++ks) {
            const int w0 = ks * 8 + 2 * hf;
            bf[ks][0] = *(const uint2*)&irow[w0];
            bf[ks][1] = *(const uint2*)&irow[w0 + 4];
        }
    }

    u32 lk[MCT];
#pragma unroll
    for (int s = 0; s < MCT; ++s) lk[s] = 0xFFFFFFFFu;
    u32 gte = 0xFFFFFFFFu;

    auto insert = [&](u32 kb) {
        if (kb < gte) {
            u32 c = kb;
#pragma unroll
            for (int t = 0; t < MCT; ++t) {
                u32 lo2 = min(c, lk[t]);
                c = max(c, lk[t]);
                lk[t] = lo2;
            }
            gte = lk[MCT - 1];
        }
    };

    for (int ch = 0; ch < NCHUNK; ++ch) {
        const int cur = ch & 1;
        // issue next-chunk global loads early (hide under MFMA+epilogue)
        float4 sv[8];
        if (ch + 1 < NCHUNK) {
            const float* src = xb + (size_t)((ch + 1) * CJ + r2) * DIM + h2 * 32;
#pragma unroll
            for (int q = 0; q < 8; ++q) sv[q] = *(const float4*)(src + q * 4);
        }
        // MFMA: wave's 2 j-tiles (its half) x 32 i, K=80 -> acc = dist+1
        const u32* jb0 = sXj + (size_t)cur * CJ * PIT + (jh * 64 + nrow) * PIT;
        const u32* jb1 = jb0 + 32 * PIT;
        f32x16 acc0, acc1;
#pragma unroll
        for (int e = 0; e < 16; ++e) { acc0[e] = 0.f; acc1[e] = 0.f; }
#pragma unroll
        for (int ks = 0; ks < 5; ++ks) {
            const int w0 = ks * 8 + 2 * hf;
            FragU A0, A1, B;
            B.u2[0] = bf[ks][0]; B.u2[1] = bf[ks][1];
            A0.u2[0] = *(const uint2*)&jb0[w0]; A0.u2[1] = *(const uint2*)&jb0[w0 + 4];
            A1.u2[0] = *(const uint2*)&jb1[w0]; A1.u2[1] = *(const uint2*)&jb1[w0 + 4];
            acc0 = __builtin_amdgcn_mfma_f32_32x32x16_bf16(A0.v, B.v, acc0, 0, 0, 0);
            acc1 = __builtin_amdgcn_mfma_f32_32x32x16_bf16(A1.v, B.v, acc1, 0, 0, 0);
        }
        // epilogue: lane-local key + register top-28 insert (no LDS)
        {
            const u32 jbase = (u32)(ch * CJ + jh * 64);
#pragma unroll
            for (int gp = 0; gp < 4; ++gp) {
#pragma unroll
                for (int e2 = 0; e2 < 4; ++e2) {
                    const int jr = 8 * gp + e2 + 4 * hf;
                    insert((__float_as_uint(acc0[4 * gp + e2]) & 0xFFFFF000u) | (jbase + jr));
                    insert((__float_as_uint(acc1[4 * gp + e2]) & 0xFFFFF000u) | (jbase + 32 + jr));
                }
            }
        }
        // write staged data into the other buffer
        if (ch + 1 < NCHUNK) stage_write(cur ^ 1, sv);
        __syncthreads();   // one barrier per chunk
    }

    // ---- dump per-lane lists: one list per (i-row, jh, hf) — 4 per row ----
    {
        const int rowi = it * 32 + nrow;
        const int lix = rowi * 4 + jh * 2 + hf;   // bijective over 256 threads
#pragma unroll
        for (int s = 0; s < MCT; ++s) mbk[lix * MCT + s] = lk[s];
    }
    __syncthreads();
    // ---- 4-way merge per row -> top-32 candidate j's ----
    if (tid < BI) {
        const u32* ls[4];
#pragma unroll
        for (int t = 0; t < 4; ++t) ls[t] = &mbk[(tid * 4 + t) * MCT];
        int p[4] = {0, 0, 0, 0};
        for (int slot = 0; slot < MROW; ++slot) {
            u32 best = 0xFFFFFFFFu; int bt = 0;
#pragma unroll
            for (int t = 0; t < 4; ++t) {
                u32 v = (p[t] < MCT) ? ls[t][p[t]] : 0xFFFFFFFFu;
                if (v < best) { best = v; bt = t; }
            }
            p[bt]++;
            sFin[tid * MROW + slot] = (int)(best & 0xFFFu);
        }
    }
    __syncthreads();

    // ---- rescore: VALIDATED R11 emulation, 8 cands/thread ----
    const int si = tid >> 2;   // row 0..63
    const int st = tid & 3;
    ull kk[RESC];
    {
        float xi_[DIM];
        const float* pxi = xb + (size_t)(i0 + si) * DIM;
#pragma unroll
        for (int d4 = 0; d4 < DIM / 4; ++d4) {
            float4 v = *(const float4*)(pxi + 4 * d4);
            xi_[4 * d4 + 0] = v.x; xi_[4 * d4 + 1] = v.y;
            xi_[4 * d4 + 2] = v.z; xi_[4 * d4 + 3] = v.w;
        }
        const float sqi32 = np_sumsq64(xi_);
#pragma unroll
        for (int c = 0; c < RESC; ++c) {
            const int j = sFin[si * MROW + st * RESC + c];
            const float* pxj = xb + (size_t)j * DIM;
            float xj_[DIM];
#pragma unroll
            for (int d4 = 0; d4 < DIM / 4; ++d4) {
                float4 v = *(const float4*)(pxj + 4 * d4);
                xj_[4 * d4 + 0] = v.x; xj_[4 * d4 + 1] = v.y;
                xj_[4 * d4 + 2] = v.z; xj_[4 * d4 + 3] = v.w;
            }
            const float inn   = np_blas_dot64(xi_, xj_);
            const float sqj32 = np_sumsq64(xj_);
            float adj32;
            {
#pragma clang fp contract(off)
                adj32 = (sqi32 - 2.0f * inn) + sqj32;
            }
            u32 bits = __float_as_uint(adj32);
            u32 mu = (bits & 0x80000000u) ? ~bits : (bits | 0x80000000u);
            kk[c] = ((ull)mu << 32) | (u32)j;
        }
    }
    for (int k = 0; k < KNN; ++k) {
        ull m = kk[0];
#pragma unroll
        for (int c = 1; c < RESC; ++c) m = kk[c] < m ? kk[c] : m;
        ull o = (ull)__shfl_xor((long long)m, 1, 4); m = o < m ? o : m;
        o = (ull)__shfl_xor((long long)m, 2, 4);     m = o < m ? o : m;
#pragma unroll
        for (int c = 0; c < RESC; ++c) if (kk[c] == m) kk[c] = ~0ull;
        if (st == 0) sFin[si * MROW + k] = (int)(m & 0xFFFFFFFFull);
    }
    __syncthreads();
    // ---- fused emit ----
    const size_t obase = (size_t)(b * NPTS + i0) * (KNN * 2 * DIM);
    for (int v = tid; v < BI * KNN * 2 * DIM / 4; v += NTH) {
        int v4 = v * 4;
        int ii = v4 / (KNN * 2 * DIM);
        int rr = v4 % (KNN * 2 * DIM);
        int k  = rr / (2 * DIM);
        int d  = rr % (2 * DIM);
        const float* crow = xb + (size_t)(i0 + ii) * DIM;
        float4 o;
        if (d < DIM) {
            o = *(const float4*)(crow + d);
        } else {
            int dd = d - DIM;
            int j  = sFin[ii * MROW + k];
            float4 n4 = *(const float4*)(xb + (size_t)j * DIM + dd);
            float4 c4 = *(const float4*)(crow + dd);
            o.x = n4.x - c4.x;
            o.y = n4.y - c4.y;
            o.z = n4.z - c4.z;
            o.w = n4.w - c4.w;
        }
        *(float4*)(out + obase + v4) = o;
    }
}

extern "C" void kernel_launch(void* const* d_in, const int* in_sizes, int n_in,
                              void* d_out, int out_size, void* d_ws, size_t ws_size,
                              hipStream_t stream) {
    const float* x = (const float*)d_in[0];
    float* out = (float*)d_out;
    dim3 grid(BATCH * (NPTS / BI));
    hipLaunchKernelGGL(edge_knn_kernel, grid, dim3(NTH), 0, stream, x, out);
}

// Round 19
// 408.307 us; speedup vs baseline: 1.0405x; 1.0405x over previous
//
#include <hip/hip_runtime.h>

#define BATCH 8
#define NPTS 4096
#define DIM 64
#define KNN 20
#define BI 32
#define CJ 128
#define MCT 16               // per-thread sorted list
#define MROW 32              // row candidates after 8-way merge
#define NTH 256
#define NCHUNK (NPTS / CJ)   // 32
#define PIT 42               // LDS row pitch in u32 words (K=80 data + pad)
#define QST 132              // queue row stride (u32)
#define MBS 17               // mbk per-thread stride
#define RESC 4               // rescore candidates per thread

typedef unsigned long long ull;
typedef unsigned int u32;
typedef __attribute__((ext_vector_type(8))) __bf16 bf16x8;
typedef __attribute__((ext_vector_type(16))) float f32x16;

union FragU { bf16x8 v; uint2 u2[2]; };

// ===== VALIDATED R11 recipes (bit-exact vs checker) — do not touch =====
__device__ __forceinline__ float np_sumsq64(const float* __restrict__ xv) {
#pragma clang fp contract(off)
    float r[8];
#pragma unroll
    for (int l = 0; l < 8; ++l) { float v = xv[1 + l]; r[l] = v * v; }
#pragma unroll
    for (int t = 1; t < 7; ++t)
#pragma unroll
        for (int l = 0; l < 8; ++l) {
            float v = xv[1 + 8 * t + l];
            float p = v * v;
            r[l] = r[l] + p;
        }
    float res = ((r[0] + r[1]) + (r[2] + r[3])) + ((r[4] + r[5]) + (r[6] + r[7]));
#pragma unroll
    for (int d = 57; d < 64; ++d) { float v = xv[d]; float p = v * v; res = res + p; }
    float a0 = xv[0] * xv[0];
    return a0 + res;
}

__device__ __forceinline__ float np_blas_dot64(const float* __restrict__ xi_,
                                               const float* __restrict__ xj_) {
    float acc = 0.f;
#pragma unroll
    for (int d = 0; d < DIM; ++d) acc = fmaf(xi_[d], xj_[d], acc);
    return acc;
}
// =======================================================================

__device__ __forceinline__ u32 packw(float a, float b) {
    return (__float_as_uint(b) & 0xFFFF0000u) | (__float_as_uint(a) >> 16);
}

__global__ __launch_bounds__(NTH, 3) void edge_knn_kernel(const float* __restrict__ x,
                                                          float* __restrict__ out) {
    // LDS: (32 + 128)*42 + 32*132 = 10944 w + qcnt/thrq = 44032 B -> 3 blocks/CU
    __shared__ __align__(16) u32 sPool[(BI + CJ) * PIT + BI * QST];
    __shared__ int qcnt[BI];
    __shared__ __align__(16) u32 thrq[BI];

    u32* sXi = sPool;                        // [32][42]
    u32* sXj = sPool + BI * PIT;             // [128][42]
    u32* sQ  = sPool + (BI + CJ) * PIT;      // [32][132]
    u32* mbk = sPool;                        // overlay after loop: 256*17 = 4352 w
    int* sFin = (int*)(sPool + 4352);        // overlay: 32*32 = 1024 w

    const int tid = threadIdx.x;
    const int blk = blockIdx.x;
    const int b   = blk >> 7;                // / (4096/32)
    const int i0  = (blk & 127) * BI;
    const float* xb = x + (size_t)b * NPTS * DIM;

    const int r2 = tid >> 1, h2 = tid & 1;

    // write one staged half-row (32 f32 in sv[8]) as bf16 + aug (K=80 format)
    auto stage_write = [&](const float4* sv) {
        u32* dst = sXj + r2 * PIT + h2 * 16;
        float ps = 0.f;
#pragma unroll
        for (int q = 0; q < 8; ++q) {
            ps = fmaf(sv[q].x, sv[q].x, ps); ps = fmaf(sv[q].y, sv[q].y, ps);
            ps = fmaf(sv[q].z, sv[q].z, ps); ps = fmaf(sv[q].w, sv[q].w, ps);
        }
#pragma unroll
        for (int q = 0; q < 4; ++q) {
            uint2 p0, p1;
            p0.x = packw(sv[2 * q].x, sv[2 * q].y);
            p0.y = packw(sv[2 * q].z, sv[2 * q].w);
            p1.x = packw(sv[2 * q + 1].x, sv[2 * q + 1].y);
            p1.y = packw(sv[2 * q + 1].z, sv[2 * q + 1].w);
            *(uint2*)&dst[q * 4]     = p0;
            *(uint2*)&dst[q * 4 + 2] = p1;
        }
        ps += __shfl_xor(ps, 1, 2);
        if (h2 == 0) {  // aug: word32 = (sqj_hi, sqj_lo), word33 = (1,1)
            u32 hib = __float_as_uint(ps) & 0xFFFF0000u;
            float lo = ps - __uint_as_float(hib);
            uint2 aug;
            aug.x = (__float_as_uint(lo) & 0xFFFF0000u) | (hib >> 16);
            aug.y = 0x3F803F80u;
            *(uint2*)&sXj[r2 * PIT + 32] = aug;
        }
    };

    // ---- prologue: Xi tile (-2*xi bf16 + aug), zero-fill, chunk-0 staging ----
    if (tid < 2 * BI) {
        const float* src = xb + (size_t)(i0 + r2) * DIM + h2 * 32;
        u32* dst = sXi + r2 * PIT + h2 * 16;
        float ps = 0.f;
#pragma unroll
        for (int q = 0; q < 4; ++q) {
            float4 va = *(const float4*)(src + q * 8);
            float4 vb = *(const float4*)(src + q * 8 + 4);
            ps = fmaf(va.x, va.x, ps); ps = fmaf(va.y, va.y, ps);
            ps = fmaf(va.z, va.z, ps); ps = fmaf(va.w, va.w, ps);
            ps = fmaf(vb.x, vb.x, ps); ps = fmaf(vb.y, vb.y, ps);
            ps = fmaf(vb.z, vb.z, ps); ps = fmaf(vb.w, vb.w, ps);
            uint2 p0, p1;
            p0.x = packw(-2.f * va.x, -2.f * va.y);
            p0.y = packw(-2.f * va.z, -2.f * va.w);
            p1.x = packw(-2.f * vb.x, -2.f * vb.y);
            p1.y = packw(-2.f * vb.z, -2.f * vb.w);
            *(uint2*)&dst[q * 4]     = p0;
            *(uint2*)&dst[q * 4 + 2] = p1;
        }
        ps += __shfl_xor(ps, 1, 2);
        if (h2 == 0) {  // aug: word32 = (1,1), word33 = (sqi1_hi, sqi1_lo)
            float sq1 = ps + 1.0f;
            u32 hib = __float_as_uint(sq1) & 0xFFFF0000u;
            float lo = sq1 - __uint_as_float(hib);
            uint2 aug;
            aug.x = 0x3F803F80u;
            aug.y = (__float_as_uint(lo) & 0xFFFF0000u) | (hib >> 16);
            *(uint2*)&sXi[r2 * PIT + 32] = aug;
        }
    }
    // zero words 34..39 of every Xi/Xj row (read by ks=4 fragments)
    for (int idx = tid; idx < (BI + CJ) * 3; idx += NTH) {
        int row = idx / 3, part = idx % 3;
        *(uint2*)&sPool[row * PIT + 34 + part * 2] = make_uint2(0u, 0u);
    }
    if (tid < BI) { qcnt[tid] = 0; thrq[tid] = 0xFFFFFFFFu; }
    {   // stage chunk 0
        const float* src = xb + (size_t)r2 * DIM + h2 * 32;
        float4 sv[8];
#pragma unroll
        for (int q = 0; q < 8; ++q) sv[q] = *(const float4*)(src + q * 4);
        stage_write(sv);
    }
    __syncthreads();

    const int lane = tid & 63, wv = tid >> 6;
    const int nrow = lane & 31, hf = lane >> 5;   // nrow = owned i-row (D[j][i])
    const int si = tid >> 3, st = tid & 7;

    // hoist Xi (B-operand) fragments into registers for the whole kernel
    uint2 bfr[5][2];
    {
        const u32* irow = sXi + nrow * PIT;
#pragma unroll
        for (int ks = 0; ks < 5; ++ks) {
            const int w0 = ks * 8 + 2 * hf;
            bfr[ks][0] = *(const uint2*)&irow[w0];
            bfr[ks][1] = *(const uint2*)&irow[w0 + 4];
        }
    }

    u32 lk[MCT];
#pragma unroll
    for (int s = 0; s < MCT; ++s) lk[s] = 0xFFFFFFFFu;

    for (int ch = 0; ch < NCHUNK; ++ch) {
        // issue next-chunk global loads early (hidden under MFMA+epilogue)
        float4 sv[8];
        if (ch + 1 < NCHUNK) {
            const float* src = xb + (size_t)((ch + 1) * CJ + r2) * DIM + h2 * 32;
#pragma unroll
            for (int q = 0; q < 8; ++q) sv[q] = *(const float4*)(src + q * 4);
        }
        // ---- MFMA: wave's 32(j) x 32(i) tile, K=80 -> acc = dist+1 ----
        const u32* jb = sXj + (wv * 32 + nrow) * PIT;
        f32x16 acc;
#pragma unroll
        for (int e = 0; e < 16; ++e) acc[e] = 0.f;
#pragma unroll
        for (int ks = 0; ks < 5; ++ks) {
            const int w0 = ks * 8 + 2 * hf;
            FragU A, B;
            B.u2[0] = bfr[ks][0]; B.u2[1] = bfr[ks][1];
            A.u2[0] = *(const uint2*)&jb[w0];
            A.u2[1] = *(const uint2*)&jb[w0 + 4];
            acc = __builtin_amdgcn_mfma_f32_32x32x16_bf16(A.v, B.v, acc, 0, 0, 0);
        }
        // ---- epilogue: lane-local filter + direct queue push ----
        {
            const u32 thr_i = thrq[nrow];
            const u32 jbase = (u32)(ch * CJ + wv * 32);
#pragma unroll
            for (int gp = 0; gp < 4; ++gp) {
#pragma unroll
                for (int e2 = 0; e2 < 4; ++e2) {
                    const int jr = 8 * gp + e2 + 4 * hf;
                    u32 kb = (__float_as_uint(acc[4 * gp + e2]) & 0xFFFFF000u) | (jbase + jr);
                    if (kb < thr_i) {
                        int idx = atomicAdd(&qcnt[nrow], 1);
                        sQ[nrow * QST + idx] = kb;
                    }
                }
            }
        }
        __syncthreads();   // (A) frag reads done; pushes visible
        if (ch + 1 < NCHUNK) stage_write(sv);   // overwrite consumed buffer
        // ---- flush: insert queue entries into per-thread sorted-16 ----
        {
            int cnt = qcnt[si];
            u32 gte = lk[MCT - 1];
            for (int q = st; q < cnt; q += 8) {
                u32 kb = sQ[si * QST + q];
                if (kb < gte) {
                    u32 cur = kb;
#pragma unroll
                    for (int t = 0; t < MCT; ++t) {
                        u32 lo = min(cur, lk[t]);
                        cur = max(cur, lk[t]);
                        lk[t] = lo;
                    }
                    gte = lk[MCT - 1];
                }
            }
            u32 m = gte;
            m = min(m, (u32)__shfl_xor((int)m, 1, 8));
            m = min(m, (u32)__shfl_xor((int)m, 2, 8));
            m = min(m, (u32)__shfl_xor((int)m, 4, 8));
            if (st == 0) { thrq[si] = m; qcnt[si] = 0; }   // same-wave lockstep
        }
        __syncthreads();   // (B) staging + flush + reset visible
    }

    // ---- dump sorted lists (pool dead) ----
#pragma unroll
    for (int s = 0; s < MCT; ++s) mbk[tid * MBS + s] = lk[s];
    __syncthreads();
    // ---- 8-way merge per row -> top-32 candidate j's ----
    if (st == 0) {
        int p[8];
#pragma unroll
        for (int t = 0; t < 8; ++t) p[t] = 0;
        for (int slot = 0; slot < MROW; ++slot) {
            u32 best = 0xFFFFFFFFu; int bt = 0;
#pragma unroll
            for (int t = 0; t < 8; ++t) {
                int pt = p[t];
                u32 v = (pt < MCT) ? mbk[(si * 8 + t) * MBS + pt] : 0xFFFFFFFFu;
                if (v < best) { best = v; bt = t; }
            }
            p[bt]++;
            sFin[si * MROW + slot] = (int)(best & 0xFFFu);
        }
    }
    __syncthreads();

    // ---- rescore: VALIDATED R11 emulation, 4 cands/thread ----
    ull kk[RESC];
    {
        float xi_[DIM];
        const float* pxi = xb + (size_t)(i0 + si) * DIM;
#pragma unroll
        for (int d4 = 0; d4 < DIM / 4; ++d4) {
            float4 v = *(const float4*)(pxi + 4 * d4);
            xi_[4 * d4 + 0] = v.x; xi_[4 * d4 + 1] = v.y;
            xi_[4 * d4 + 2] = v.z; xi_[4 * d4 + 3] = v.w;
        }
        const float sqi32 = np_sumsq64(xi_);
#pragma unroll
        for (int c = 0; c < RESC; ++c) {
            const int j = sFin[si * MROW + st * RESC + c];
            const float* pxj = xb + (size_t)j * DIM;
            float xj_[DIM];
#pragma unroll
            for (int d4 = 0; d4 < DIM / 4; ++d4) {
                float4 v = *(const float4*)(pxj + 4 * d4);
                xj_[4 * d4 + 0] = v.x; xj_[4 * d4 + 1] = v.y;
                xj_[4 * d4 + 2] = v.z; xj_[4 * d4 + 3] = v.w;
            }
            const float inn   = np_blas_dot64(xi_, xj_);
            const float sqj32 = np_sumsq64(xj_);
            float adj32;
            {
#pragma clang fp contract(off)
                adj32 = (sqi32 - 2.0f * inn) + sqj32;
            }
            u32 bits = __float_as_uint(adj32);
            u32 mu = (bits & 0x80000000u) ? ~bits : (bits | 0x80000000u);
            kk[c] = ((ull)mu << 32) | (u32)j;
        }
    }
    for (int k = 0; k < KNN; ++k) {
        ull m01 = kk[0] < kk[1] ? kk[0] : kk[1];
        ull m23 = kk[2] < kk[3] ? kk[2] : kk[3];
        ull m = m01 < m23 ? m01 : m23;
#pragma unroll
        for (int w = 1; w < 8; w <<= 1) {
            ull o = (ull)__shfl_xor((long long)m, w, 8);
            m = o < m ? o : m;
        }
#pragma unroll
        for (int c = 0; c < RESC; ++c) if (kk[c] == m) kk[c] = ~0ull;
        if (st == 0) sFin[si * MROW + k] = (int)(m & 0xFFFFFFFFull);
    }
    __syncthreads();
    // ---- fused emit ----
    const size_t obase = (size_t)(b * NPTS + i0) * (KNN * 2 * DIM);
    for (int v = tid; v < BI * KNN * 2 * DIM / 4; v += NTH) {
        int v4 = v * 4;
        int ii = v4 / (KNN * 2 * DIM);
        int rr = v4 % (KNN * 2 * DIM);
        int k  = rr / (2 * DIM);
        int d  = rr % (2 * DIM);
        const float* crow = xb + (size_t)(i0 + ii) * DIM;
        float4 o;
        if (d < DIM) {
            o = *(const float4*)(crow + d);
        } else {
            int dd = d - DIM;
            int j  = sFin[ii * MROW + k];
            float4 n4 = *(const float4*)(xb + (size_t)j * DIM + dd);
            float4 c4 = *(const float4*)(crow + dd);
            o.x = n4.x - c4.x;
            o.y = n4.y - c4.y;
            o.z = n4.z - c4.z;
            o.w = n4.w - c4.w;
        }
        *(float4*)(out + obase + v4) = o;
    }
}

extern "C" void kernel_launch(void* const* d_in, const int* in_sizes, int n_in,
                              void* d_out, int out_size, void* d_ws, size_t ws_size,
                              hipStream_t stream) {
    const float* x = (const float*)d_in[0];
    float* out = (float*)d_out;
    dim3 grid(BATCH * (NPTS / BI));
    hipLaunchKernelGGL(edge_knn_kernel, grid, dim3(NTH), 0, stream, x, out);
}